// Round 6
// baseline (29.832 us; speedup 1.0000x reference)
//
#include <hip/hip_runtime.h>
#include <hip/hip_fp16.h>

constexpr int H  = 8;
constexpr int T  = 2048;
constexpr int DH = 64;
constexpr int D  = 64;
constexpr int NKV = H * T * DH;   // 1M elements per tensor

typedef _Float16 half2v __attribute__((ext_vector_type(2)));

#if defined(__has_builtin)
#if __has_builtin(__builtin_amdgcn_fdot2)
#define HAVE_FDOT2 1
#endif
#endif

__device__ __forceinline__ float dot2acc(half2v a, half2v b, float c) {
#ifdef HAVE_FDOT2
    return __builtin_amdgcn_fdot2(a, b, c, false);
#else
    return c + (float)a.x * (float)b.x + (float)a.y * (float)b.y;
#endif
}

__device__ __forceinline__ half2v h2add(half2v a, int braw) {
    half2v b = __builtin_bit_cast(half2v, braw);
    return a + b;   // v_pk_add_f16
}

// ---- fused prepass ----
// job 0/1/2: f32 -> f16 convert of k / v / q.
// job 3: pack metadata: for each (flat,n): {s_clamped | msk<<31, bias_bits}.
__global__ __launch_bounds__(256) void prepass(
    const float* __restrict__ q, const float* __restrict__ k,
    const float* __restrict__ v, const float* __restrict__ eb,
    const int* __restrict__ nidx, const int* __restrict__ etyp,
    __half* __restrict__ qh, __half* __restrict__ kh, __half* __restrict__ vh,
    int2* __restrict__ meta)
{
    const int job  = blockIdx.y;
    const int base = (blockIdx.x * 256 + threadIdx.x) * 8;
    if (job < 3) {
        const float* src = (job == 0) ? k : (job == 1) ? v : q;
        __half*      dst = (job == 0) ? kh : (job == 1) ? vh : qh;
        const float4 a = *reinterpret_cast<const float4*>(src + base);
        const float4 b = *reinterpret_cast<const float4*>(src + base + 4);
        __half2 hh[4];
        hh[0] = __float22half2_rn(make_float2(a.x, a.y));
        hh[1] = __float22half2_rn(make_float2(a.z, a.w));
        hh[2] = __float22half2_rn(make_float2(b.x, b.y));
        hh[3] = __float22half2_rn(make_float2(b.z, b.w));
        *reinterpret_cast<float4*>(dst + base) = *reinterpret_cast<const float4*>(hh);
    } else {
        const int4 i0 = *reinterpret_cast<const int4*>(nidx + base);
        const int4 i1 = *reinterpret_cast<const int4*>(nidx + base + 4);
        const int4 e0 = *reinterpret_cast<const int4*>(etyp + base);
        const int4 e1 = *reinterpret_cast<const int4*>(etyp + base + 4);
        const int  t  = (base >> 6) & (T - 1);        // 8 | 64, so one row
        const float4 ebv = *reinterpret_cast<const float4*>(eb);
        const int idx[8] = {i0.x, i0.y, i0.z, i0.w, i1.x, i1.y, i1.z, i1.w};
        const int et [8] = {e0.x, e0.y, e0.z, e0.w, e1.x, e1.y, e1.z, e1.w};
        int2 m[8];
        #pragma unroll
        for (int j = 0; j < 8; ++j) {
            const int  s   = min(max(idx[j], 0), T - 1);
            const bool msk = (idx[j] >= 0) && (idx[j] <= t);
            const int  e   = et[j];
            const float bias = (e == 1) ? ebv.x : (e == 2) ? ebv.y :
                               (e == 3) ? ebv.z : (e == 4) ? ebv.w : 0.0f;
            m[j].x = s | (msk ? 0x80000000 : 0);
            m[j].y = __float_as_int(bias);
        }
        int2* mp = meta + base;
        #pragma unroll
        for (int j = 0; j < 4; ++j)
            *reinterpret_cast<int4*>(mp + j * 2) =
                *reinterpret_cast<const int4*>(&m[j * 2]);
    }
}

// ---- main: fp16 q/k/v, packed meta, no LDS/barriers, XCD-head affinity ----
__global__ __launch_bounds__(256) void wayfinder_attn_f16(
    const __half* __restrict__ qh,
    const __half* __restrict__ kh,
    const __half* __restrict__ vh,
    const int2*   __restrict__ meta,
    float* __restrict__ out)
{
    const int wave = threadIdx.x >> 6;
    const int lane = threadIdx.x & 63;
    const int bid  = blockIdx.x;
    const int work = ((bid & 7) << 9) | (bid >> 3);   // XCD i <-> head i
    const int flat = (work << 2) + wave;              // h*T + t
    const int h    = flat >> 11;
    const int grp  = lane >> 3;
    const int sub  = lane & 7;

    const long long rowoff = (long long)flat * DH;
    const int2*     mrow   = meta + (long long)flat * D;

    // packed metadata, directly in gather layout (8 broadcast dwordx2)
    int2 m[8];
    #pragma unroll
    for (int i = 0; i < 8; ++i) m[i] = mrow[i * 8 + grp];

    // q fragment fp16: channels sub*8 .. sub*8+7 in one dwordx4
    const float4 qraw = *reinterpret_cast<const float4*>(qh + rowoff + sub * 8);
    const half2v* qp  = reinterpret_cast<const half2v*>(&qraw);

    const __half* khead = kh + (long long)h * T * DH;
    const __half* vhead = vh + (long long)h * T * DH;

    // K gathers: one dwordx4 = full fp16 row per 8-lane group
    float4 kf[8];
    #pragma unroll
    for (int i = 0; i < 8; ++i) {
        const int s = m[i].x & 0x7fffffff;
        kf[i] = *reinterpret_cast<const float4*>(khead + (long long)s * DH + sub * 8);
    }

    // QK: 4 fdot2 per row + 3 intra-group shfl levels
    float sc[8];
    #pragma unroll
    for (int i = 0; i < 8; ++i) {
        const half2v* kp = reinterpret_cast<const half2v*>(&kf[i]);
        float p = dot2acc(qp[0], kp[0],
                  dot2acc(qp[1], kp[1],
                  dot2acc(qp[2], kp[2],
                  dot2acc(qp[3], kp[3], 0.0f))));
        p += __shfl_xor(p, 1);
        p += __shfl_xor(p, 2);
        p += __shfl_xor(p, 4);
        sc[i] = p;
    }

    // keep V gathers AFTER QK so kf's registers are dead first
    __builtin_amdgcn_sched_barrier(0);

    float4 vf[8];
    #pragma unroll
    for (int i = 0; i < 8; ++i) {
        const int s = m[i].x & 0x7fffffff;
        vf[i] = *reinterpret_cast<const float4*>(vhead + (long long)s * DH + sub * 8);
    }

    // masked softmax: local over 8 entries, then 3 cross-group shfl levels
    bool  msk[8];
    float masked[8];
    float mx = -1e30f;
    #pragma unroll
    for (int i = 0; i < 8; ++i) {
        msk[i]    = m[i].x < 0;
        masked[i] = msk[i] ? fmaf(sc[i], 0.125f, __int_as_float(m[i].y)) : -1e30f;
        mx = fmaxf(mx, masked[i]);
    }
    mx = fmaxf(mx, __shfl_xor(mx, 8));
    mx = fmaxf(mx, __shfl_xor(mx, 16));
    mx = fmaxf(mx, __shfl_xor(mx, 32));

    float e[8];
    float sum = 0.0f;
    #pragma unroll
    for (int i = 0; i < 8; ++i) {
        e[i] = msk[i] ? __expf(masked[i] - mx) : 0.0f;
        sum += e[i];
    }
    sum += __shfl_xor(sum, 8);
    sum += __shfl_xor(sum, 16);
    sum += __shfl_xor(sum, 32);
    const float rden = 1.0f / fmaxf(sum, 1e-9f);

    // PV in f32 from registers
    float acc[8] = {0.f, 0.f, 0.f, 0.f, 0.f, 0.f, 0.f, 0.f};
    #pragma unroll
    for (int i = 0; i < 8; ++i) {
        const float w = e[i] * rden;
        const half2v* vp = reinterpret_cast<const half2v*>(&vf[i]);
        acc[0] += w * (float)vp[0].x;  acc[1] += w * (float)vp[0].y;
        acc[2] += w * (float)vp[1].x;  acc[3] += w * (float)vp[1].y;
        acc[4] += w * (float)vp[2].x;  acc[5] += w * (float)vp[2].y;
        acc[6] += w * (float)vp[3].x;  acc[7] += w * (float)vp[3].y;
    }

    // cross-group reduce on packed halves: 12 swizzles instead of 24
    half2v h0 = {(_Float16)acc[0], (_Float16)acc[1]};
    half2v h1 = {(_Float16)acc[2], (_Float16)acc[3]};
    half2v h2 = {(_Float16)acc[4], (_Float16)acc[5]};
    half2v h3 = {(_Float16)acc[6], (_Float16)acc[7]};
    #pragma unroll
    for (int off = 8; off <= 32; off <<= 1) {
        h0 = h2add(h0, __shfl_xor(__builtin_bit_cast(int, h0), off));
        h1 = h2add(h1, __shfl_xor(__builtin_bit_cast(int, h1), off));
        h2 = h2add(h2, __shfl_xor(__builtin_bit_cast(int, h2), off));
        h3 = h2add(h3, __shfl_xor(__builtin_bit_cast(int, h3), off));
    }

    if (lane < 16) {
        const int s8   = (lane & 7) * 8;
        const int half = lane >> 3;
        const float4 o = half
            ? make_float4((float)h2.x, (float)h2.y, (float)h3.x, (float)h3.y)
            : make_float4((float)h0.x, (float)h0.y, (float)h1.x, (float)h1.y);
        *reinterpret_cast<float4*>(out + rowoff + s8 + half * 4) = o;
    }
}

// ---- fallback: f32 kernel (used if ws too small) ----
__global__ __launch_bounds__(256) void wayfinder_attn_f32(
    const float* __restrict__ q, const float* __restrict__ k,
    const float* __restrict__ v, const float* __restrict__ eb,
    const int* __restrict__ nidx, const int* __restrict__ etyp,
    float* __restrict__ out)
{
    const int wave = threadIdx.x >> 6;
    const int lane = threadIdx.x & 63;
    const int flat = (blockIdx.x << 2) + wave;
    const int h    = flat >> 11;
    const int t    = flat & (T - 1);
    const int grp  = lane >> 4;
    const int sub  = lane & 15;

    __shared__ int    sidx[4][64];
    __shared__ float  ssc [4][64];
    __shared__ float2 swv [4][64];

    const long long rowoff = (long long)flat * DH;
    const long long noff = (long long)flat * D + lane;
    const int  idx = nidx[noff];
    const int  et  = etyp[noff];
    const int  s   = min(max(idx, 0), T - 1);
    const bool msk = (idx >= 0) && (idx <= t);
    const float4 ebv  = *reinterpret_cast<const float4*>(eb);
    const float  bias = (et == 1) ? ebv.x : (et == 2) ? ebv.y :
                        (et == 3) ? ebv.z : (et == 4) ? ebv.w : 0.0f;
    sidx[wave][lane] = s;
    const float4 qf = *reinterpret_cast<const float4*>(q + rowoff + sub * 4);
    __syncthreads();

    const float* khead = k + (long long)h * T * DH;
    #pragma unroll
    for (int i = 0; i < 16; ++i) {
        const int n  = i * 4 + grp;
        const int sn = sidx[wave][n];
        const float4 kf = *reinterpret_cast<const float4*>(khead + sn * DH + sub * 4);
        float p = qf.x * kf.x + qf.y * kf.y + qf.z * kf.z + qf.w * kf.w;
        p += __shfl_xor(p, 1);
        p += __shfl_xor(p, 2);
        p += __shfl_xor(p, 4);
        p += __shfl_xor(p, 8);
        if (sub == 0) ssc[wave][n] = p;
    }
    __syncthreads();

    const float sc     = ssc[wave][lane];
    const float masked = msk ? (sc * 0.125f + bias) : -1e30f;
    float mx = masked;
    #pragma unroll
    for (int off = 32; off > 0; off >>= 1) mx = fmaxf(mx, __shfl_xor(mx, off));
    const float e = msk ? __expf(masked - mx) : 0.0f;
    float sum = e;
    #pragma unroll
    for (int off = 32; off > 0; off >>= 1) sum += __shfl_xor(sum, off);
    const float w = e / fmaxf(sum, 1e-9f);
    swv[wave][lane] = make_float2(w, __int_as_float(s));
    __syncthreads();

    const float* vhead = v + (long long)h * T * DH;
    float4 acc = make_float4(0.f, 0.f, 0.f, 0.f);
    #pragma unroll
    for (int i = 0; i < 16; ++i) {
        const int    n  = i * 4 + grp;
        const float2 ws = swv[wave][n];
        const int    sn = __float_as_int(ws.y);
        const float4 vf = *reinterpret_cast<const float4*>(vhead + sn * DH + sub * 4);
        acc.x += ws.x * vf.x; acc.y += ws.x * vf.y;
        acc.z += ws.x * vf.z; acc.w += ws.x * vf.w;
    }
    #pragma unroll
    for (int off = 16; off <= 32; off <<= 1) {
        acc.x += __shfl_xor(acc.x, off); acc.y += __shfl_xor(acc.y, off);
        acc.z += __shfl_xor(acc.z, off); acc.w += __shfl_xor(acc.w, off);
    }
    if (lane < 16)
        *reinterpret_cast<float4*>(out + rowoff + sub * 4) = acc;
}

extern "C" void kernel_launch(void* const* d_in, const int* in_sizes, int n_in,
                              void* d_out, int out_size, void* d_ws, size_t ws_size,
                              hipStream_t stream) {
    const float* q    = (const float*)d_in[0];
    const float* k    = (const float*)d_in[1];
    const float* v    = (const float*)d_in[2];
    const float* eb   = (const float*)d_in[3];
    const int*   nidx = (const int*)d_in[4];
    const int*   etyp = (const int*)d_in[5];
    float* out = (float*)d_out;

    // ws layout: kh(2MB) | vh(2MB) | qh(2MB) | meta(8MB)
    const size_t need = (size_t)3 * NKV * sizeof(__half) + (size_t)NKV * sizeof(int2);
    if (ws_size >= need) {
        __half* kh = (__half*)d_ws;
        __half* vh = kh + NKV;
        __half* qh = vh + NKV;
        int2*   mt = (int2*)(qh + NKV);
        dim3 pgrid(NKV / (256 * 8), 4);
        hipLaunchKernelGGL(prepass, pgrid, dim3(256), 0, stream,
                           q, k, v, eb, nidx, etyp, qh, kh, vh, mt);
        hipLaunchKernelGGL(wayfinder_attn_f16, dim3(H * T / 4), dim3(256), 0, stream,
                           qh, kh, vh, mt, out);
    } else {
        hipLaunchKernelGGL(wayfinder_attn_f32, dim3(H * T / 4), dim3(256), 0, stream,
                           q, k, v, eb, nidx, etyp, out);
    }
}

// Round 7
// 25.466 us; speedup vs baseline: 1.1714x; 1.1714x over previous
//
#include <hip/hip_runtime.h>
#include <hip/hip_fp16.h>

constexpr int H  = 8;
constexpr int T  = 2048;
constexpr int DH = 64;
constexpr int D  = 64;
constexpr int NKV = H * T * DH;   // 1M elements per tensor

typedef _Float16 half2v __attribute__((ext_vector_type(2)));

#if defined(__has_builtin)
#if __has_builtin(__builtin_amdgcn_fdot2)
#define HAVE_FDOT2 1
#endif
#endif

__device__ __forceinline__ float dot2acc(half2v a, half2v b, float c) {
#ifdef HAVE_FDOT2
    return __builtin_amdgcn_fdot2(a, b, c, false);
#else
    return c + (float)a.x * (float)b.x + (float)a.y * (float)b.y;
#endif
}

__device__ __forceinline__ half2v h2add(half2v a, int braw) {
    half2v b = __builtin_bit_cast(half2v, braw);
    return a + b;   // v_pk_add_f16
}

__device__ __forceinline__ half2v f2h2(float x, float y) {
    __half2 h = __float22half2_rn(make_float2(x, y));
    return __builtin_bit_cast(half2v, h);
}

// ---- prepass: f32 -> f16 for k and v only (12 MB streamed) ----
__global__ __launch_bounds__(256) void cvt_f32_f16(
    const float* __restrict__ k, const float* __restrict__ v,
    __half* __restrict__ kh, __half* __restrict__ vh)
{
    const int i = (blockIdx.x * 256 + threadIdx.x) * 8;
    const float* src = (blockIdx.y == 0) ? k : v;
    __half*      dst = (blockIdx.y == 0) ? kh : vh;
    const float4 a = *reinterpret_cast<const float4*>(src + i);
    const float4 b = *reinterpret_cast<const float4*>(src + i + 4);
    __half2 hh[4];
    hh[0] = __float22half2_rn(make_float2(a.x, a.y));
    hh[1] = __float22half2_rn(make_float2(a.z, a.w));
    hh[2] = __float22half2_rn(make_float2(b.x, b.y));
    hh[3] = __float22half2_rn(make_float2(b.z, b.w));
    *reinterpret_cast<float4*>(dst + i) = *reinterpret_cast<const float4*>(hh);
}

// ---- main: fp16 k/v gathers, no LDS/barriers, XCD-head affinity ----
// grp = lane>>3 (row-group), sub = lane&7 (8-channel slice).
// Register entry i <-> neighbor n = i*8 + grp. Metadata loaded DIRECTLY in
// this layout (tiny broadcast loads -> addresses form with no shfl chain).
// K AND V gathers issue together up front: 16 independent loads in flight,
// V latency hides under QK + softmax. q converted fp32->fp16 in-register
// so QK uses v_dot2_f32_f16.
__global__ __launch_bounds__(256) void wayfinder_attn_f16(
    const float* __restrict__ q,
    const __half* __restrict__ kh,
    const __half* __restrict__ vh,
    const float* __restrict__ eb,
    const int*   __restrict__ nidx,
    const int*   __restrict__ etyp,
    float* __restrict__ out)
{
    const int wave = threadIdx.x >> 6;
    const int lane = threadIdx.x & 63;
    const int bid  = blockIdx.x;
    const int work = ((bid & 7) << 9) | (bid >> 3);   // XCD i <-> head i
    const int flat = (work << 2) + wave;              // h*T + t
    const int h    = flat >> 11;
    const int t    = flat & (T - 1);
    const int grp  = lane >> 3;
    const int sub  = lane & 7;

    const long long rowoff = (long long)flat * DH;
    const int*      nrow   = nidx + (long long)flat * D;
    const int*      erow   = etyp + (long long)flat * D;

    // metadata directly in gather layout: entry i = neighbor i*8+grp
    int idx_i[8], et_i[8];
    #pragma unroll
    for (int i = 0; i < 8; ++i) idx_i[i] = nrow[i * 8 + grp];
    #pragma unroll
    for (int i = 0; i < 8; ++i) et_i[i]  = erow[i * 8 + grp];

    // q fragment: channels sub*8 .. sub*8+7, f32 load then in-register fp16
    const float4 qa = *reinterpret_cast<const float4*>(q + rowoff + sub * 8);
    const float4 qb = *reinterpret_cast<const float4*>(q + rowoff + sub * 8 + 4);
    half2v qp[4];
    qp[0] = f2h2(qa.x, qa.y);
    qp[1] = f2h2(qa.z, qa.w);
    qp[2] = f2h2(qb.x, qb.y);
    qp[3] = f2h2(qb.z, qb.w);

    const __half* khead = kh + (long long)h * T * DH;
    const __half* vhead = vh + (long long)h * T * DH;

    // K and V gathers together: one dwordx4 = full fp16 row per 8-lane group
    float4 kf[8], vf[8];
    #pragma unroll
    for (int i = 0; i < 8; ++i) {
        const int s = min(max(idx_i[i], 0), T - 1);
        const long long ro = (long long)s * DH + sub * 8;
        kf[i] = *reinterpret_cast<const float4*>(khead + ro);
        vf[i] = *reinterpret_cast<const float4*>(vhead + ro);
    }

    const float4 ebv = *reinterpret_cast<const float4*>(eb);

    // QK: 4 fdot2 per row + 3 intra-group shfl levels
    float sc[8];
    #pragma unroll
    for (int i = 0; i < 8; ++i) {
        const half2v* kp = reinterpret_cast<const half2v*>(&kf[i]);
        float p = dot2acc(qp[0], kp[0],
                  dot2acc(qp[1], kp[1],
                  dot2acc(qp[2], kp[2],
                  dot2acc(qp[3], kp[3], 0.0f))));
        p += __shfl_xor(p, 1);
        p += __shfl_xor(p, 2);
        p += __shfl_xor(p, 4);
        sc[i] = p;
    }

    // masked softmax: local over 8 entries, then 3 cross-group shfl levels
    bool  msk[8];
    float masked[8];
    float mx = -1e30f;
    #pragma unroll
    for (int i = 0; i < 8; ++i) {
        const int et = et_i[i];
        const float bias = (et == 1) ? ebv.x : (et == 2) ? ebv.y :
                           (et == 3) ? ebv.z : (et == 4) ? ebv.w : 0.0f;
        msk[i]    = (idx_i[i] >= 0) && (idx_i[i] <= t);
        masked[i] = msk[i] ? fmaf(sc[i], 0.125f, bias) : -1e30f;
        mx = fmaxf(mx, masked[i]);
    }
    mx = fmaxf(mx, __shfl_xor(mx, 8));
    mx = fmaxf(mx, __shfl_xor(mx, 16));
    mx = fmaxf(mx, __shfl_xor(mx, 32));

    float e[8];
    float sum = 0.0f;
    #pragma unroll
    for (int i = 0; i < 8; ++i) {
        e[i] = msk[i] ? __expf(masked[i] - mx) : 0.0f;
        sum += e[i];
    }
    sum += __shfl_xor(sum, 8);
    sum += __shfl_xor(sum, 16);
    sum += __shfl_xor(sum, 32);
    const float rden = 1.0f / fmaxf(sum, 1e-9f);

    // PV in f32 from registers (weights already in this layout)
    float acc[8] = {0.f, 0.f, 0.f, 0.f, 0.f, 0.f, 0.f, 0.f};
    #pragma unroll
    for (int i = 0; i < 8; ++i) {
        const float w = e[i] * rden;
        const half2v* vp = reinterpret_cast<const half2v*>(&vf[i]);
        acc[0] += w * (float)vp[0].x;  acc[1] += w * (float)vp[0].y;
        acc[2] += w * (float)vp[1].x;  acc[3] += w * (float)vp[1].y;
        acc[4] += w * (float)vp[2].x;  acc[5] += w * (float)vp[2].y;
        acc[6] += w * (float)vp[3].x;  acc[7] += w * (float)vp[3].y;
    }

    // cross-group reduce on packed halves: 12 swizzles instead of 24
    half2v h0 = f2h2(acc[0], acc[1]);
    half2v h1 = f2h2(acc[2], acc[3]);
    half2v h2 = f2h2(acc[4], acc[5]);
    half2v h3 = f2h2(acc[6], acc[7]);
    #pragma unroll
    for (int off = 8; off <= 32; off <<= 1) {
        h0 = h2add(h0, __shfl_xor(__builtin_bit_cast(int, h0), off));
        h1 = h2add(h1, __shfl_xor(__builtin_bit_cast(int, h1), off));
        h2 = h2add(h2, __shfl_xor(__builtin_bit_cast(int, h2), off));
        h3 = h2add(h3, __shfl_xor(__builtin_bit_cast(int, h3), off));
    }

    if (lane < 16) {
        const int s8   = (lane & 7) * 8;
        const int half = lane >> 3;
        const float4 o = half
            ? make_float4((float)h2.x, (float)h2.y, (float)h3.x, (float)h3.y)
            : make_float4((float)h0.x, (float)h0.y, (float)h1.x, (float)h1.y);
        *reinterpret_cast<float4*>(out + rowoff + s8 + half * 4) = o;
    }
}

// ---- fallback: f32 kernel (used if ws too small) ----
__global__ __launch_bounds__(256) void wayfinder_attn_f32(
    const float* __restrict__ q, const float* __restrict__ k,
    const float* __restrict__ v, const float* __restrict__ eb,
    const int* __restrict__ nidx, const int* __restrict__ etyp,
    float* __restrict__ out)
{
    const int wave = threadIdx.x >> 6;
    const int lane = threadIdx.x & 63;
    const int flat = (blockIdx.x << 2) + wave;
    const int h    = flat >> 11;
    const int t    = flat & (T - 1);
    const int grp  = lane >> 4;
    const int sub  = lane & 15;

    __shared__ int    sidx[4][64];
    __shared__ float  ssc [4][64];
    __shared__ float2 swv [4][64];

    const long long rowoff = (long long)flat * DH;
    const long long noff = (long long)flat * D + lane;
    const int  idx = nidx[noff];
    const int  et  = etyp[noff];
    const int  s   = min(max(idx, 0), T - 1);
    const bool msk = (idx >= 0) && (idx <= t);
    const float4 ebv  = *reinterpret_cast<const float4*>(eb);
    const float  bias = (et == 1) ? ebv.x : (et == 2) ? ebv.y :
                        (et == 3) ? ebv.z : (et == 4) ? ebv.w : 0.0f;
    sidx[wave][lane] = s;
    const float4 qf = *reinterpret_cast<const float4*>(q + rowoff + sub * 4);
    __syncthreads();

    const float* khead = k + (long long)h * T * DH;
    #pragma unroll
    for (int i = 0; i < 16; ++i) {
        const int n  = i * 4 + grp;
        const int sn = sidx[wave][n];
        const float4 kf = *reinterpret_cast<const float4*>(khead + sn * DH + sub * 4);
        float p = qf.x * kf.x + qf.y * kf.y + qf.z * kf.z + qf.w * kf.w;
        p += __shfl_xor(p, 1);
        p += __shfl_xor(p, 2);
        p += __shfl_xor(p, 4);
        p += __shfl_xor(p, 8);
        if (sub == 0) ssc[wave][n] = p;
    }
    __syncthreads();

    const float sc     = ssc[wave][lane];
    const float masked = msk ? (sc * 0.125f + bias) : -1e30f;
    float mx = masked;
    #pragma unroll
    for (int off = 32; off > 0; off >>= 1) mx = fmaxf(mx, __shfl_xor(mx, off));
    const float e = msk ? __expf(masked - mx) : 0.0f;
    float sum = e;
    #pragma unroll
    for (int off = 32; off > 0; off >>= 1) sum += __shfl_xor(sum, off);
    const float w = e / fmaxf(sum, 1e-9f);
    swv[wave][lane] = make_float2(w, __int_as_float(s));
    __syncthreads();

    const float* vhead = v + (long long)h * T * DH;
    float4 acc = make_float4(0.f, 0.f, 0.f, 0.f);
    #pragma unroll
    for (int i = 0; i < 16; ++i) {
        const int    n  = i * 4 + grp;
        const float2 ws = swv[wave][n];
        const int    sn = __float_as_int(ws.y);
        const float4 vf = *reinterpret_cast<const float4*>(vhead + sn * DH + sub * 4);
        acc.x += ws.x * vf.x; acc.y += ws.x * vf.y;
        acc.z += ws.x * vf.z; acc.w += ws.x * vf.w;
    }
    #pragma unroll
    for (int off = 16; off <= 32; off <<= 1) {
        acc.x += __shfl_xor(acc.x, off); acc.y += __shfl_xor(acc.y, off);
        acc.z += __shfl_xor(acc.z, off); acc.w += __shfl_xor(acc.w, off);
    }
    if (lane < 16)
        *reinterpret_cast<float4*>(out + rowoff + sub * 4) = acc;
}

extern "C" void kernel_launch(void* const* d_in, const int* in_sizes, int n_in,
                              void* d_out, int out_size, void* d_ws, size_t ws_size,
                              hipStream_t stream) {
    const float* q    = (const float*)d_in[0];
    const float* k    = (const float*)d_in[1];
    const float* v    = (const float*)d_in[2];
    const float* eb   = (const float*)d_in[3];
    const int*   nidx = (const int*)d_in[4];
    const int*   etyp = (const int*)d_in[5];
    float* out = (float*)d_out;

    const size_t need = (size_t)2 * NKV * sizeof(__half);   // 4 MB
    if (ws_size >= need) {
        __half* kh = (__half*)d_ws;
        __half* vh = kh + NKV;
        dim3 cgrid(NKV / (256 * 8), 2);
        hipLaunchKernelGGL(cvt_f32_f16, cgrid, dim3(256), 0, stream, k, v, kh, vh);
        hipLaunchKernelGGL(wayfinder_attn_f16, dim3(H * T / 4), dim3(256), 0, stream,
                           q, kh, vh, eb, nidx, etyp, out);
    } else {
        hipLaunchKernelGGL(wayfinder_attn_f32, dim3(H * T / 4), dim3(256), 0, stream,
                           q, k, v, eb, nidx, etyp, out);
    }
}